// Round 3
// baseline (86070.111 us; speedup 1.0000x reference)
//
#include <hip/hip_runtime.h>

#define HD 64
#define WD 64
#define HW 4096
#define BATCH 2

// ---------------- feat = concat(inputs[2b+a0], inputs[2b+a1]) (f32 -> f64) ---
__global__ void pack_feat_d(const float* __restrict__ in, double* __restrict__ dst,
                            int a0, int a1) {
    int idx = blockIdx.x * 256 + threadIdx.x;
    if (idx >= BATCH * 256 * HW) return;
    int i = idx % HW;
    int c = (idx / HW) & 255;
    int b = idx / (HW * 256);
    int sb = 2 * b + ((c < 128) ? a0 : a1);
    dst[idx] = (double)in[((size_t)(sb * 128 + (c & 127))) * HW + i];
}

// ---------------- direct conv3x3, pad=1, fp64 --------------------------------
__global__ void conv3x3_d(const double* __restrict__ src, int bstride,
                          const float* __restrict__ w, double* __restrict__ dst,
                          int Ci, int O, int relu) {
    int idx = blockIdx.x * 256 + threadIdx.x;
    int total = BATCH * O * HW;
    if (idx >= total) return;
    int x = idx % WD;
    int h = (idx / WD) % HD;
    int o = (idx / HW) % O;
    int b = idx / (HW * O);
    const double* s  = src + (size_t)b * bstride;
    const float*  wo = w + (size_t)o * Ci * 9;
    double acc = 0.0;
    for (int c = 0; c < Ci; ++c) {
        const double* sc = s + c * HW;
        const float*  wc = wo + c * 9;
#pragma unroll
        for (int kh = 0; kh < 3; ++kh) {
            int y = h + kh - 1;
            if ((unsigned)y >= (unsigned)HD) continue;
#pragma unroll
            for (int kw = 0; kw < 3; ++kw) {
                int xx = x + kw - 1;
                if ((unsigned)xx >= (unsigned)WD) continue;
                acc = fma(sc[y * WD + xx], (double)wc[kh * 3 + kw], acc);
            }
        }
    }
    if (relu) acc = fmax(acc, 0.0);
    dst[idx] = acc;
}

// ---------------- reference-exact deformable conv, fp64 ----------------------
// One thread per output element (b,o,h,x). Original weight layout (O,Ci,3,3).
// ST = source dtype (float for raw inputs, double for staged feats).
template <typename ST>
__global__ void deform_simple_d(const ST* __restrict__ src, int src_bstride,
                                const double* __restrict__ off,
                                const float* __restrict__ w,
                                double* __restrict__ dst, int Ci, int O) {
    int idx = blockIdx.x * 256 + threadIdx.x;
    int total = BATCH * O * HW;
    if (idx >= total) return;
    int x = idx % WD;
    int h = (idx / WD) % HD;
    int o = (idx / HW) % O;
    int b = idx / (HW * O);
    const ST*    srcb = src + (size_t)b * src_bstride;
    const float* wo   = w + (size_t)o * Ci * 9;
    double acc = 0.0;
    for (int k = 0; k < 9; ++k) {
        double dy = off[((size_t)(b * 18 + 2 * k)     * HD + h) * WD + x];
        double dx = off[((size_t)(b * 18 + 2 * k + 1) * HD + h) * WD + x];
        double py  = dy + (double)(k / 3 - 1 + h);
        double pxf = dx + (double)(k % 3 - 1 + x);
        double y0f = floor(py), x0f = floor(pxf);
        double wy1 = py - y0f, wx1 = pxf - x0f;
        double wy0 = 1.0 - wy1, wx0 = 1.0 - wx1;
        // positions are O(1); direct int conversion is safe, but clamp anyway
        int y0 = (y0f < -1e9) ? -1000000 : ((y0f > 1e9) ? 1000000 : (int)y0f);
        int x0 = (x0f < -1e9) ? -1000000 : ((x0f > 1e9) ? 1000000 : (int)x0f);
        int y1 = y0 + 1,   x1 = x0 + 1;
        bool vy0 = (y0 >= 0 && y0 < HD), vy1 = (y1 >= 0 && y1 < HD);
        bool vx0 = (x0 >= 0 && x0 < WD), vx1 = (x1 >= 0 && x1 < WD);
        int yc0 = min(max(y0, 0), HD - 1), yc1 = min(max(y1, 0), HD - 1);
        int xc0 = min(max(x0, 0), WD - 1), xc1 = min(max(x1, 0), WD - 1);
        int a00 = yc0 * WD + xc0, a01 = yc0 * WD + xc1;
        int a10 = yc1 * WD + xc0, a11 = yc1 * WD + xc1;
        double w00 = (vy0 && vx0) ? wy0 * wx0 : 0.0;
        double w01 = (vy0 && vx1) ? wy0 * wx1 : 0.0;
        double w10 = (vy1 && vx0) ? wy1 * wx0 : 0.0;
        double w11 = (vy1 && vx1) ? wy1 * wx1 : 0.0;
        for (int c = 0; c < Ci; ++c) {
            const ST* p = srcb + (size_t)c * HW;
            double v = w00 * (double)p[a00] + w01 * (double)p[a01]
                     + w10 * (double)p[a10] + w11 * (double)p[a11];
            acc = fma(v, (double)wo[c * 9 + k], acc);
        }
    }
    dst[idx] = acc;
}

// ---------------- fusion: cos-sim -> softmax -> blend, fp64 ------------------
__global__ void fuse_d(const double* __restrict__ d0, const double* __restrict__ d1,
                       const double* __restrict__ w0, const double* __restrict__ w1,
                       float* __restrict__ out) {
    int idx = blockIdx.x * 256 + threadIdx.x;
    if (idx >= BATCH * 128 * HW) return;
    int i = idx % HW;
    int b = idx / (128 * HW);
    double a  = w0[b * HW + i];
    double bb = w1[b * HW + i];
    // cos sim exactly as reference: num/sqrt(max(sum(a*a)*sum(b*b), EPS^2))
    double Wx = (a * bb) / sqrt(fmax((a * a) * (bb * bb), 1e-16));
    double Wy = (bb * bb) / sqrt(fmax((bb * bb) * (bb * bb), 1e-16));
    double m  = fmax(Wx, Wy);
    double e0 = exp(Wx - m), e1 = exp(Wy - m);
    double inv = 1.0 / (e0 + e1);
    out[idx] = (float)((d0[idx] * e0 + d1[idx] * e1) * inv);
}

// ---------------- launch -----------------------------------------------------
extern "C" void kernel_launch(void* const* d_in, const int* in_sizes, int n_in,
                              void* d_out, int out_size, void* d_ws, size_t ws_size,
                              hipStream_t stream) {
    const float* inputs = (const float*)d_in[2];
    const float* off_w[4] = {(const float*)d_in[3], (const float*)d_in[4],
                             (const float*)d_in[5], (const float*)d_in[6]};
    const float* def_w[3] = {(const float*)d_in[7], (const float*)d_in[8],
                             (const float*)d_in[9]};
    const float* pred_w = (const float*)d_in[10];
    const float* s_w[3] = {(const float*)d_in[11], (const float*)d_in[12],
                           (const float*)d_in[13]};
    float* out = (float*)d_out;

    // workspace layout (doubles)
    double* ws = (double*)d_ws;
    size_t o = 0;
    double* featA   = ws + o; o += (size_t)BATCH * 256 * HW;
    double* featB   = ws + o; o += (size_t)BATCH * 256 * HW;
    double* offb    = ws + o; o += (size_t)BATCH * 18 * HW;
    double* offset0 = ws + o; o += (size_t)BATCH * 18 * HW;
    double* offset1 = ws + o; o += (size_t)BATCH * 18 * HW;
    double* deform0 = ws + o; o += (size_t)BATCH * 128 * HW;
    double* deform1 = ws + o; o += (size_t)BATCH * 128 * HW;
    double* s1      = ws + o; o += (size_t)BATCH * 64 * HW;
    double* s2      = ws + o; o += (size_t)BATCH * 32 * HW;
    double* w0buf   = ws + o; o += (size_t)BATCH * HW;
    double* w1buf   = ws + o; o += (size_t)BATCH * HW;
    if (ws_size < o * sizeof(double)) return;  // workspace too small

    auto cdiv = [](int a, int b) { return (a + b - 1) / b; };

    for (int branch = 0; branch < 2; ++branch) {
        int a0 = (branch == 0) ? 0 : 1;
        double* offsetN  = (branch == 0) ? offset0 : offset1;
        double* deformN  = (branch == 0) ? deform0 : deform1;
        double* wbufN    = (branch == 0) ? w0buf : w1buf;
        const float* xy  = (branch == 0) ? inputs : inputs + 128 * HW;  // x or y

        pack_feat_d<<<cdiv(BATCH * 256 * HW, 256), 256, 0, stream>>>(inputs, featA, a0, 1);

        double* cur = featA;
        double* nxt = featB;
        for (int i = 0; i < 3; ++i) {
            conv3x3_d<<<cdiv(BATCH * 18 * HW, 256), 256, 0, stream>>>(
                cur, 256 * HW, off_w[i], offb, 256, 18, 0);
            deform_simple_d<double><<<cdiv(BATCH * 256 * HW, 256), 256, 0, stream>>>(
                cur, 256 * HW, offb, def_w[i], nxt, 256, 256);
            double* tmp = cur; cur = nxt; nxt = tmp;
        }
        conv3x3_d<<<cdiv(BATCH * 18 * HW, 256), 256, 0, stream>>>(
            cur, 256 * HW, off_w[3], offsetN, 256, 18, 0);

        // pred deform conv on x (or y): source is raw fp32 inputs, stride 2*128*HW
        deform_simple_d<float><<<cdiv(BATCH * 128 * HW, 256), 256, 0, stream>>>(
            xy, 2 * 128 * HW, offsetN, pred_w, deformN, 128, 128);

        // S-net
        conv3x3_d<<<cdiv(BATCH * 64 * HW, 256), 256, 0, stream>>>(
            deformN, 128 * HW, s_w[0], s1, 128, 64, 1);
        conv3x3_d<<<cdiv(BATCH * 32 * HW, 256), 256, 0, stream>>>(
            s1, 64 * HW, s_w[1], s2, 64, 32, 1);
        conv3x3_d<<<cdiv(BATCH * 1 * HW, 256), 256, 0, stream>>>(
            s2, 32 * HW, s_w[2], wbufN, 32, 1, 1);
    }

    fuse_d<<<cdiv(BATCH * 128 * HW, 256), 256, 0, stream>>>(
        deform0, deform1, w0buf, w1buf, out);
}

// Round 4
// 6137.599 us; speedup vs baseline: 14.0234x; 14.0234x over previous
//
#include <hip/hip_runtime.h>

#define HD 64
#define WD 64
#define HW 4096
#define BATCH 2

// ---------------- weight transpose: w[o][c][k] -> wt[(c*9+k)*O + o] (fp32) ---
__global__ void transpose_w_k(const float* __restrict__ w, float* __restrict__ wt,
                              int O, int Ci) {
    int idx = blockIdx.x * 256 + threadIdx.x;
    int total = O * Ci * 9;
    if (idx >= total) return;
    int k = idx % 9;
    int c = (idx / 9) % Ci;
    int o = idx / (9 * Ci);
    wt[(size_t)(c * 9 + k) * O + o] = w[idx];
}

// ---------------- feat = concat(inputs[2b+a0], inputs[2b+1]) (f32 -> f64) ----
__global__ void pack_feat_d(const float* __restrict__ in, double* __restrict__ dst,
                            int a0) {
    int idx = blockIdx.x * 256 + threadIdx.x;
    if (idx >= BATCH * 256 * HW) return;
    int i = idx % HW;
    int c = (idx / HW) & 255;
    int b = idx / (HW * 256);
    int sb = 2 * b + ((c < 128) ? a0 : 1);
    dst[idx] = (double)in[((size_t)(sb * 128 + (c & 127))) * HW + i];
}

// ---------------- fused deformable conv + GEMM, fp64 -------------------------
// Block = O threads; thread t: og=t>>2 (4 o's), pg=t&3 (4 px). 16-px tile.
template <int O, int CC, typename ST>
__global__ __launch_bounds__(O) void deform_gemm_d(
    const ST* __restrict__ src, int src_bstride,
    const double* __restrict__ off,
    const float* __restrict__ wt,   // [(c*9+k)*O + o]
    double* __restrict__ dst, int Ci) {
    int px0 = blockIdx.x * 16;
    int h   = blockIdx.y;
    int b   = blockIdx.z;
    int t   = threadIdx.x;
    int og  = t >> 2;
    int pg  = t & 3;

    __shared__ double s_samp[CC][9][16];
    __shared__ int    s_addr[9][16][4];
    __shared__ double s_w4[9][16][4];

    // phase 1: 144 sampling positions (shared across all channels)
    for (int i = t; i < 144; i += O) {
        int k = i / 16, px = i % 16, wc = px0 + px;
        double dy = off[((size_t)(b * 18 + 2 * k)     * HD + h) * WD + wc];
        double dx = off[((size_t)(b * 18 + 2 * k + 1) * HD + h) * WD + wc];
        double py  = dy + (double)(k / 3 - 1 + h);
        double pxf = dx + (double)(k % 3 - 1 + wc);
        double y0f = floor(py), x0f = floor(pxf);
        double wy1 = py - y0f, wx1 = pxf - x0f;
        double wy0 = 1.0 - wy1, wx0 = 1.0 - wx1;
        double y0c = fmax(-2.0, fmin(66.0, y0f));
        double x0c = fmax(-2.0, fmin(66.0, x0f));
        int y0 = (int)y0c, x0 = (int)x0c;
        int y1 = y0 + 1,   x1 = x0 + 1;
        bool vy0 = (y0 >= 0 && y0 < HD), vy1 = (y1 >= 0 && y1 < HD);
        bool vx0 = (x0 >= 0 && x0 < WD), vx1 = (x1 >= 0 && x1 < WD);
        int yc0 = min(max(y0, 0), HD - 1), yc1 = min(max(y1, 0), HD - 1);
        int xc0 = min(max(x0, 0), WD - 1), xc1 = min(max(x1, 0), WD - 1);
        s_addr[k][px][0] = yc0 * WD + xc0;
        s_addr[k][px][1] = yc0 * WD + xc1;
        s_addr[k][px][2] = yc1 * WD + xc0;
        s_addr[k][px][3] = yc1 * WD + xc1;
        s_w4[k][px][0] = (vy0 && vx0) ? wy0 * wx0 : 0.0;
        s_w4[k][px][1] = (vy0 && vx1) ? wy0 * wx1 : 0.0;
        s_w4[k][px][2] = (vy1 && vx0) ? wy1 * wx0 : 0.0;
        s_w4[k][px][3] = (vy1 && vx1) ? wy1 * wx1 : 0.0;
    }
    __syncthreads();

    double acc[4][4];
#pragma unroll
    for (int a = 0; a < 4; ++a)
#pragma unroll
        for (int p = 0; p < 4; ++p) acc[a][p] = 0.0;

    const ST* srcb = src + (size_t)b * src_bstride;
    for (int c0 = 0; c0 < Ci; c0 += CC) {
        // stage CC channels of bilinear samples
        for (int i = t; i < CC * 144; i += O) {
            int px = i % 16, k = (i / 16) % 9, c = i / 144;
            const ST* p = srcb + (size_t)(c0 + c) * HW;
            const int*    ad = s_addr[k][px];
            const double* w4 = s_w4[k][px];
            s_samp[c][k][px] = w4[0] * (double)p[ad[0]] + w4[1] * (double)p[ad[1]]
                             + w4[2] * (double)p[ad[2]] + w4[3] * (double)p[ad[3]];
        }
        __syncthreads();
        for (int c = 0; c < CC; ++c) {
#pragma unroll
            for (int k = 0; k < 9; ++k) {
                const float4 wv = *(const float4*)&wt[(size_t)((c0 + c) * 9 + k) * O + og * 4];
                const double* sp = &s_samp[c][k][pg * 4];
                double s0 = sp[0], s1 = sp[1], s2 = sp[2], s3 = sp[3];
                double w0 = (double)wv.x, w1 = (double)wv.y,
                       w2 = (double)wv.z, w3 = (double)wv.w;
                acc[0][0] = fma(w0, s0, acc[0][0]);
                acc[0][1] = fma(w0, s1, acc[0][1]);
                acc[0][2] = fma(w0, s2, acc[0][2]);
                acc[0][3] = fma(w0, s3, acc[0][3]);
                acc[1][0] = fma(w1, s0, acc[1][0]);
                acc[1][1] = fma(w1, s1, acc[1][1]);
                acc[1][2] = fma(w1, s2, acc[1][2]);
                acc[1][3] = fma(w1, s3, acc[1][3]);
                acc[2][0] = fma(w2, s0, acc[2][0]);
                acc[2][1] = fma(w2, s1, acc[2][1]);
                acc[2][2] = fma(w2, s2, acc[2][2]);
                acc[2][3] = fma(w2, s3, acc[2][3]);
                acc[3][0] = fma(w3, s0, acc[3][0]);
                acc[3][1] = fma(w3, s1, acc[3][1]);
                acc[3][2] = fma(w3, s2, acc[3][2]);
                acc[3][3] = fma(w3, s3, acc[3][3]);
            }
        }
        __syncthreads();
    }
#pragma unroll
    for (int oi = 0; oi < 4; ++oi) {
        double* d = dst + ((size_t)(b * O + og * 4 + oi) * HD + h) * WD + px0 + pg * 4;
#pragma unroll
        for (int pi = 0; pi < 4; ++pi) d[pi] = acc[oi][pi];
    }
}

// ---------------- conv3x3 as GEMM w/ LDS im2col, fp64 ------------------------
// Grid (2, HD, B): 32-px tiles. Block (8, OPAD/4): thread = 4 o x 4 px.
template <int OPAD, int CC>
__global__ void conv_gemm_d(const double* __restrict__ src, int bstride,
                            const float* __restrict__ w,   // [o][ci*9] original
                            double* __restrict__ dst, int Ci, int O, int relu) {
    int px0 = blockIdx.x * 32;
    int h   = blockIdx.y;
    int b   = blockIdx.z;
    int tx  = threadIdx.x;            // 0..7, px = px0 + tx*4 ..+3
    int ty  = threadIdx.y;            // 0..OPAD/4-1, o = ty*4 ..+3
    int t     = ty * 8 + tx;
    const int nthr = 8 * (OPAD / 4);

    __shared__ double s_rows[CC][3][34];   // cols px0-1 .. px0+32 (idx = x-px0+1)
    __shared__ float  s_wt[CC * 9][OPAD];

    double acc[4][4];
#pragma unroll
    for (int a = 0; a < 4; ++a)
#pragma unroll
        for (int p = 0; p < 4; ++p) acc[a][p] = 0.0;

    const double* sb = src + (size_t)b * bstride;
    for (int c0 = 0; c0 < Ci; c0 += CC) {
        for (int i = t; i < CC * 3 * 34; i += nthr) {
            int col = i % 34;
            int r   = (i / 34) % 3;
            int c   = i / 102;
            int x = px0 + col - 1;
            int y = h + r - 1;
            double v = 0.0;
            if ((unsigned)x < (unsigned)WD && (unsigned)y < (unsigned)HD)
                v = sb[(size_t)(c0 + c) * HW + y * WD + x];
            s_rows[c][r][col] = v;
        }
        for (int i = t; i < CC * 9 * OPAD; i += nthr) {
            int o  = i % OPAD;
            int ck = i / OPAD;
            int c = ck / 9, k = ck % 9;
            s_wt[ck][o] = (o < O) ? w[((size_t)o * Ci + (c0 + c)) * 9 + k] : 0.f;
        }
        __syncthreads();
        for (int c = 0; c < CC; ++c) {
#pragma unroll
            for (int kh = 0; kh < 3; ++kh) {
                const double* rp = &s_rows[c][kh][tx * 4];
                double r0 = rp[0], r1 = rp[1], r2 = rp[2],
                       r3 = rp[3], r4 = rp[4], r5 = rp[5];
#pragma unroll
                for (int kw = 0; kw < 3; ++kw) {
                    const float4 wv = *(const float4*)&s_wt[c * 9 + kh * 3 + kw][ty * 4];
                    double w0 = (double)wv.x, w1 = (double)wv.y,
                           w2 = (double)wv.z, w3 = (double)wv.w;
                    double t0 = (kw == 0) ? r0 : ((kw == 1) ? r1 : r2);
                    double t1 = (kw == 0) ? r1 : ((kw == 1) ? r2 : r3);
                    double t2 = (kw == 0) ? r2 : ((kw == 1) ? r3 : r4);
                    double t3 = (kw == 0) ? r3 : ((kw == 1) ? r4 : r5);
                    acc[0][0] = fma(w0, t0, acc[0][0]);
                    acc[0][1] = fma(w0, t1, acc[0][1]);
                    acc[0][2] = fma(w0, t2, acc[0][2]);
                    acc[0][3] = fma(w0, t3, acc[0][3]);
                    acc[1][0] = fma(w1, t0, acc[1][0]);
                    acc[1][1] = fma(w1, t1, acc[1][1]);
                    acc[1][2] = fma(w1, t2, acc[1][2]);
                    acc[1][3] = fma(w1, t3, acc[1][3]);
                    acc[2][0] = fma(w2, t0, acc[2][0]);
                    acc[2][1] = fma(w2, t1, acc[2][1]);
                    acc[2][2] = fma(w2, t2, acc[2][2]);
                    acc[2][3] = fma(w2, t3, acc[2][3]);
                    acc[3][0] = fma(w3, t0, acc[3][0]);
                    acc[3][1] = fma(w3, t1, acc[3][1]);
                    acc[3][2] = fma(w3, t2, acc[3][2]);
                    acc[3][3] = fma(w3, t3, acc[3][3]);
                }
            }
        }
        __syncthreads();
    }
#pragma unroll
    for (int oi = 0; oi < 4; ++oi) {
        int o = ty * 4 + oi;
        if (o < O) {
            double* d = dst + ((size_t)(b * O + o) * HD + h) * WD + px0 + tx * 4;
#pragma unroll
            for (int pi = 0; pi < 4; ++pi) {
                double v = acc[oi][pi];
                if (relu) v = fmax(v, 0.0);
                d[pi] = v;
            }
        }
    }
}

// ---------------- simple per-element conv (only for O=1 final S-conv) --------
__global__ void conv3x3_d(const double* __restrict__ src, int bstride,
                          const float* __restrict__ w, double* __restrict__ dst,
                          int Ci, int O, int relu) {
    int idx = blockIdx.x * 256 + threadIdx.x;
    int total = BATCH * O * HW;
    if (idx >= total) return;
    int x = idx % WD;
    int h = (idx / WD) % HD;
    int o = (idx / HW) % O;
    int b = idx / (HW * O);
    const double* s  = src + (size_t)b * bstride;
    const float*  wo = w + (size_t)o * Ci * 9;
    double acc = 0.0;
    for (int c = 0; c < Ci; ++c) {
        const double* sc = s + c * HW;
        const float*  wc = wo + c * 9;
#pragma unroll
        for (int kh = 0; kh < 3; ++kh) {
            int y = h + kh - 1;
            if ((unsigned)y >= (unsigned)HD) continue;
#pragma unroll
            for (int kw = 0; kw < 3; ++kw) {
                int xx = x + kw - 1;
                if ((unsigned)xx >= (unsigned)WD) continue;
                acc = fma(sc[y * WD + xx], (double)wc[kh * 3 + kw], acc);
            }
        }
    }
    if (relu) acc = fmax(acc, 0.0);
    dst[idx] = acc;
}

// ---------------- fusion: cos-sim -> softmax -> blend, fp64 ------------------
__global__ void fuse_d(const double* __restrict__ d0, const double* __restrict__ d1,
                       const double* __restrict__ w0, const double* __restrict__ w1,
                       float* __restrict__ out) {
    int idx = blockIdx.x * 256 + threadIdx.x;
    if (idx >= BATCH * 128 * HW) return;
    int i = idx % HW;
    int b = idx / (128 * HW);
    double a  = w0[b * HW + i];
    double bb = w1[b * HW + i];
    double Wx = (a * bb) / sqrt(fmax((a * a) * (bb * bb), 1e-16));
    double Wy = (bb * bb) / sqrt(fmax((bb * bb) * (bb * bb), 1e-16));
    double m  = fmax(Wx, Wy);
    double e0 = exp(Wx - m), e1 = exp(Wy - m);
    double inv = 1.0 / (e0 + e1);
    out[idx] = (float)((d0[idx] * e0 + d1[idx] * e1) * inv);
}

// ---------------- launch -----------------------------------------------------
extern "C" void kernel_launch(void* const* d_in, const int* in_sizes, int n_in,
                              void* d_out, int out_size, void* d_ws, size_t ws_size,
                              hipStream_t stream) {
    const float* inputs = (const float*)d_in[2];
    const float* off_w[4] = {(const float*)d_in[3], (const float*)d_in[4],
                             (const float*)d_in[5], (const float*)d_in[6]};
    const float* def_w[3] = {(const float*)d_in[7], (const float*)d_in[8],
                             (const float*)d_in[9]};
    const float* pred_w = (const float*)d_in[10];
    const float* s_w[3] = {(const float*)d_in[11], (const float*)d_in[12],
                           (const float*)d_in[13]};
    float* out = (float*)d_out;

    // workspace layout (double units; fp32 regions at the end, 16B-aligned)
    double* ws = (double*)d_ws;
    size_t o = 0;
    double* featA   = ws + o; o += (size_t)BATCH * 256 * HW;
    double* featB   = ws + o; o += (size_t)BATCH * 256 * HW;
    double* offb    = ws + o; o += (size_t)BATCH * 18 * HW;
    double* offset0 = ws + o; o += (size_t)BATCH * 18 * HW;
    double* offset1 = ws + o; o += (size_t)BATCH * 18 * HW;
    double* deform0 = ws + o; o += (size_t)BATCH * 128 * HW;
    double* deform1 = ws + o; o += (size_t)BATCH * 128 * HW;
    double* s1      = ws + o; o += (size_t)BATCH * 64 * HW;
    double* s2      = ws + o; o += (size_t)BATCH * 32 * HW;
    double* w0buf   = ws + o; o += (size_t)BATCH * HW;
    double* w1buf   = ws + o; o += (size_t)BATCH * HW;
    float* wtdef0 = (float*)(ws + o); o += (size_t)256 * 256 * 9 / 2;
    float* wtdef1 = (float*)(ws + o); o += (size_t)256 * 256 * 9 / 2;
    float* wtdef2 = (float*)(ws + o); o += (size_t)256 * 256 * 9 / 2;
    float* wtpred = (float*)(ws + o); o += (size_t)128 * 128 * 9 / 2;
    if (ws_size < o * sizeof(double)) return;  // workspace too small

    auto cdiv = [](int a, int b) { return (a + b - 1) / b; };

    transpose_w_k<<<cdiv(256 * 256 * 9, 256), 256, 0, stream>>>(def_w[0], wtdef0, 256, 256);
    transpose_w_k<<<cdiv(256 * 256 * 9, 256), 256, 0, stream>>>(def_w[1], wtdef1, 256, 256);
    transpose_w_k<<<cdiv(256 * 256 * 9, 256), 256, 0, stream>>>(def_w[2], wtdef2, 256, 256);
    transpose_w_k<<<cdiv(128 * 128 * 9, 256), 256, 0, stream>>>(pred_w, wtpred, 128, 128);
    const float* wtdef[3] = {wtdef0, wtdef1, wtdef2};

    dim3 dgrid(WD / 16, HD, BATCH);
    dim3 cgrid(WD / 32, HD, BATCH);

    for (int branch = 0; branch < 2; ++branch) {
        int a0 = (branch == 0) ? 0 : 1;
        double* offsetN  = (branch == 0) ? offset0 : offset1;
        double* deformN  = (branch == 0) ? deform0 : deform1;
        double* wbufN    = (branch == 0) ? w0buf : w1buf;
        const float* xy  = (branch == 0) ? inputs : inputs + 128 * HW;

        pack_feat_d<<<cdiv(BATCH * 256 * HW, 256), 256, 0, stream>>>(inputs, featA, a0);

        double* cur = featA;
        double* nxt = featB;
        for (int i = 0; i < 3; ++i) {
            conv_gemm_d<32, 8><<<cgrid, dim3(8, 8), 0, stream>>>(
                cur, 256 * HW, off_w[i], offb, 256, 18, 0);
            deform_gemm_d<256, 32, double><<<dgrid, 256, 0, stream>>>(
                cur, 256 * HW, offb, wtdef[i], nxt, 256);
            double* tmp = cur; cur = nxt; nxt = tmp;
        }
        conv_gemm_d<32, 8><<<cgrid, dim3(8, 8), 0, stream>>>(
            cur, 256 * HW, off_w[3], offsetN, 256, 18, 0);

        deform_gemm_d<128, 32, float><<<dgrid, 128, 0, stream>>>(
            xy, 2 * 128 * HW, offsetN, wtpred, deformN, 128);

        conv_gemm_d<64, 8><<<cgrid, dim3(8, 16), 0, stream>>>(
            deformN, 128 * HW, s_w[0], s1, 128, 64, 1);
        conv_gemm_d<32, 8><<<cgrid, dim3(8, 8), 0, stream>>>(
            s1, 64 * HW, s_w[1], s2, 64, 32, 1);
        conv3x3_d<<<cdiv(BATCH * 1 * HW, 256), 256, 0, stream>>>(
            s2, 32 * HW, s_w[2], wbufN, 32, 1, 1);
    }

    fuse_d<<<cdiv(BATCH * 128 * HW, 256), 256, 0, stream>>>(
        deform0, deform1, w0buf, w1buf, out);
}

// Round 5
// 5105.637 us; speedup vs baseline: 16.8579x; 1.2021x over previous
//
#include <hip/hip_runtime.h>

#define HD 64
#define WD 64
#define HW 4096
#define BATCH 2

// ---------------- weight transpose: w[o][c][k] -> wt[(c*9+k)*O + o] (fp32) ---
__global__ void transpose_w_k(const float* __restrict__ w, float* __restrict__ wt,
                              int O, int Ci) {
    int idx = blockIdx.x * 256 + threadIdx.x;
    int total = O * Ci * 9;
    if (idx >= total) return;
    int k = idx % 9;
    int c = (idx / 9) % Ci;
    int o = idx / (9 * Ci);
    wt[(size_t)(c * 9 + k) * O + o] = w[idx];
}

// ---------------- feat = concat(inputs[2b+a0], inputs[2b+1]) (f32 -> f64) ----
__global__ void pack_feat_d(const float* __restrict__ in, double* __restrict__ dst,
                            int a0) {
    int idx = blockIdx.x * 256 + threadIdx.x;
    if (idx >= BATCH * 256 * HW) return;
    int i = idx % HW;
    int c = (idx / HW) & 255;
    int b = idx / (HW * 256);
    int sb = 2 * b + ((c < 128) ? a0 : 1);
    dst[idx] = (double)in[((size_t)(sb * 128 + (c & 127))) * HW + i];
}

// ---------------- direct conv3x3, one thread per output, fp64 ----------------
// idx = (b*O + o)*HW + h*WD + x ; weights wave-uniform (same o per block).
__global__ __launch_bounds__(256) void conv3x3_direct_d(
    const double* __restrict__ src, int bstride,
    const float* __restrict__ w, double* __restrict__ dst,
    int Ci, int O, int relu) {
    int idx = blockIdx.x * 256 + threadIdx.x;
    int total = BATCH * O * HW;
    if (idx >= total) return;
    int x = idx & (WD - 1);
    int h = (idx >> 6) & (HD - 1);
    int rest = idx >> 12;
    int o = rest % O;
    int b = rest / O;
    const double* s  = src + (size_t)b * bstride + h * WD + x;
    const float*  wo = w + (size_t)o * Ci * 9;
    bool ym = (h > 0), yp = (h < HD - 1);
    bool xm = (x > 0), xp = (x < WD - 1);
    double a0 = 0.0, a1 = 0.0, a2 = 0.0;   // one chain per kh row
    for (int c = 0; c < Ci; ++c) {
        const double* sc = s + (size_t)c * HW;
        const float*  wc = wo + c * 9;
        if (ym) {
            double v0 = xm ? sc[-WD - 1] : 0.0;
            double v1 = sc[-WD];
            double v2 = xp ? sc[-WD + 1] : 0.0;
            a0 = fma(v0, (double)wc[0], a0);
            a0 = fma(v1, (double)wc[1], a0);
            a0 = fma(v2, (double)wc[2], a0);
        }
        {
            double v0 = xm ? sc[-1] : 0.0;
            double v1 = sc[0];
            double v2 = xp ? sc[1] : 0.0;
            a1 = fma(v0, (double)wc[3], a1);
            a1 = fma(v1, (double)wc[4], a1);
            a1 = fma(v2, (double)wc[5], a1);
        }
        if (yp) {
            double v0 = xm ? sc[WD - 1] : 0.0;
            double v1 = sc[WD];
            double v2 = xp ? sc[WD + 1] : 0.0;
            a2 = fma(v0, (double)wc[6], a2);
            a2 = fma(v1, (double)wc[7], a2);
            a2 = fma(v2, (double)wc[8], a2);
        }
    }
    double acc = (a0 + a1) + a2;
    if (relu) acc = fmax(acc, 0.0);
    dst[idx] = acc;
}

// ---------------- fused deformable conv + GEMM, fp64 -------------------------
// Block = O threads; thread t: og=t>>2 (4 o's), pg=t&3 (4 px). 16-px tile.
template <int O, int CC, typename ST>
__global__ __launch_bounds__(O) void deform_gemm_d(
    const ST* __restrict__ src, int src_bstride,
    const double* __restrict__ off,
    const float* __restrict__ wt,   // [(c*9+k)*O + o]
    double* __restrict__ dst, int Ci) {
    int px0 = blockIdx.x * 16;
    int h   = blockIdx.y;
    int b   = blockIdx.z;
    int t   = threadIdx.x;
    int og  = t >> 2;
    int pg  = t & 3;

    __shared__ double s_samp[CC][9][16];
    __shared__ int    s_addr[9][16][4];
    __shared__ double s_w4[9][16][4];

    // phase 1: 144 sampling positions (shared across all channels)
    for (int i = t; i < 144; i += O) {
        int k = i / 16, px = i % 16, wc = px0 + px;
        double dy = off[((size_t)(b * 18 + 2 * k)     * HD + h) * WD + wc];
        double dx = off[((size_t)(b * 18 + 2 * k + 1) * HD + h) * WD + wc];
        double py  = dy + (double)(k / 3 - 1 + h);
        double pxf = dx + (double)(k % 3 - 1 + wc);
        double y0f = floor(py), x0f = floor(pxf);
        double wy1 = py - y0f, wx1 = pxf - x0f;
        double wy0 = 1.0 - wy1, wx0 = 1.0 - wx1;
        double y0c = fmax(-2.0, fmin(66.0, y0f));
        double x0c = fmax(-2.0, fmin(66.0, x0f));
        int y0 = (int)y0c, x0 = (int)x0c;
        int y1 = y0 + 1,   x1 = x0 + 1;
        bool vy0 = (y0 >= 0 && y0 < HD), vy1 = (y1 >= 0 && y1 < HD);
        bool vx0 = (x0 >= 0 && x0 < WD), vx1 = (x1 >= 0 && x1 < WD);
        int yc0 = min(max(y0, 0), HD - 1), yc1 = min(max(y1, 0), HD - 1);
        int xc0 = min(max(x0, 0), WD - 1), xc1 = min(max(x1, 0), WD - 1);
        s_addr[k][px][0] = yc0 * WD + xc0;
        s_addr[k][px][1] = yc0 * WD + xc1;
        s_addr[k][px][2] = yc1 * WD + xc0;
        s_addr[k][px][3] = yc1 * WD + xc1;
        s_w4[k][px][0] = (vy0 && vx0) ? wy0 * wx0 : 0.0;
        s_w4[k][px][1] = (vy0 && vx1) ? wy0 * wx1 : 0.0;
        s_w4[k][px][2] = (vy1 && vx0) ? wy1 * wx0 : 0.0;
        s_w4[k][px][3] = (vy1 && vx1) ? wy1 * wx1 : 0.0;
    }
    __syncthreads();

    double acc[4][4];
#pragma unroll
    for (int a = 0; a < 4; ++a)
#pragma unroll
        for (int p = 0; p < 4; ++p) acc[a][p] = 0.0;

    const ST* srcb = src + (size_t)b * src_bstride;
    for (int c0 = 0; c0 < Ci; c0 += CC) {
        // stage CC channels of bilinear samples
        for (int i = t; i < CC * 144; i += O) {
            int px = i % 16, k = (i / 16) % 9, c = i / 144;
            const ST* p = srcb + (size_t)(c0 + c) * HW;
            const int*    ad = s_addr[k][px];
            const double* w4 = s_w4[k][px];
            s_samp[c][k][px] = w4[0] * (double)p[ad[0]] + w4[1] * (double)p[ad[1]]
                             + w4[2] * (double)p[ad[2]] + w4[3] * (double)p[ad[3]];
        }
        __syncthreads();
        for (int c = 0; c < CC; ++c) {
#pragma unroll
            for (int k = 0; k < 9; ++k) {
                const float4 wv = *(const float4*)&wt[(size_t)((c0 + c) * 9 + k) * O + og * 4];
                const double* sp = &s_samp[c][k][pg * 4];
                double s0 = sp[0], s1 = sp[1], s2 = sp[2], s3 = sp[3];
                double w0 = (double)wv.x, w1 = (double)wv.y,
                       w2 = (double)wv.z, w3 = (double)wv.w;
                acc[0][0] = fma(w0, s0, acc[0][0]);
                acc[0][1] = fma(w0, s1, acc[0][1]);
                acc[0][2] = fma(w0, s2, acc[0][2]);
                acc[0][3] = fma(w0, s3, acc[0][3]);
                acc[1][0] = fma(w1, s0, acc[1][0]);
                acc[1][1] = fma(w1, s1, acc[1][1]);
                acc[1][2] = fma(w1, s2, acc[1][2]);
                acc[1][3] = fma(w1, s3, acc[1][3]);
                acc[2][0] = fma(w2, s0, acc[2][0]);
                acc[2][1] = fma(w2, s1, acc[2][1]);
                acc[2][2] = fma(w2, s2, acc[2][2]);
                acc[2][3] = fma(w2, s3, acc[2][3]);
                acc[3][0] = fma(w3, s0, acc[3][0]);
                acc[3][1] = fma(w3, s1, acc[3][1]);
                acc[3][2] = fma(w3, s2, acc[3][2]);
                acc[3][3] = fma(w3, s3, acc[3][3]);
            }
        }
        __syncthreads();
    }
#pragma unroll
    for (int oi = 0; oi < 4; ++oi) {
        double* d = dst + ((size_t)(b * O + og * 4 + oi) * HD + h) * WD + px0 + pg * 4;
#pragma unroll
        for (int pi = 0; pi < 4; ++pi) d[pi] = acc[oi][pi];
    }
}

// ---------------- fusion: cos-sim -> softmax -> blend, fp64 ------------------
__global__ void fuse_d(const double* __restrict__ d0, const double* __restrict__ d1,
                       const double* __restrict__ w0, const double* __restrict__ w1,
                       float* __restrict__ out) {
    int idx = blockIdx.x * 256 + threadIdx.x;
    if (idx >= BATCH * 128 * HW) return;
    int i = idx % HW;
    int b = idx / (128 * HW);
    double a  = w0[b * HW + i];
    double bb = w1[b * HW + i];
    double Wx = (a * bb) / sqrt(fmax((a * a) * (bb * bb), 1e-16));
    double Wy = (bb * bb) / sqrt(fmax((bb * bb) * (bb * bb), 1e-16));
    double m  = fmax(Wx, Wy);
    double e0 = exp(Wx - m), e1 = exp(Wy - m);
    double inv = 1.0 / (e0 + e1);
    out[idx] = (float)((d0[idx] * e0 + d1[idx] * e1) * inv);
}

// ---------------- launch -----------------------------------------------------
extern "C" void kernel_launch(void* const* d_in, const int* in_sizes, int n_in,
                              void* d_out, int out_size, void* d_ws, size_t ws_size,
                              hipStream_t stream) {
    const float* inputs = (const float*)d_in[2];
    const float* off_w[4] = {(const float*)d_in[3], (const float*)d_in[4],
                             (const float*)d_in[5], (const float*)d_in[6]};
    const float* def_w[3] = {(const float*)d_in[7], (const float*)d_in[8],
                             (const float*)d_in[9]};
    const float* pred_w = (const float*)d_in[10];
    const float* s_w[3] = {(const float*)d_in[11], (const float*)d_in[12],
                           (const float*)d_in[13]};
    float* out = (float*)d_out;

    // workspace layout (double units; fp32 regions at the end, 16B-aligned)
    double* ws = (double*)d_ws;
    size_t o = 0;
    double* featA   = ws + o; o += (size_t)BATCH * 256 * HW;
    double* featB   = ws + o; o += (size_t)BATCH * 256 * HW;
    double* offb    = ws + o; o += (size_t)BATCH * 18 * HW;
    double* offset0 = ws + o; o += (size_t)BATCH * 18 * HW;
    double* offset1 = ws + o; o += (size_t)BATCH * 18 * HW;
    double* deform0 = ws + o; o += (size_t)BATCH * 128 * HW;
    double* deform1 = ws + o; o += (size_t)BATCH * 128 * HW;
    double* s1      = ws + o; o += (size_t)BATCH * 64 * HW;
    double* s2      = ws + o; o += (size_t)BATCH * 32 * HW;
    double* w0buf   = ws + o; o += (size_t)BATCH * HW;
    double* w1buf   = ws + o; o += (size_t)BATCH * HW;
    float* wtdef0 = (float*)(ws + o); o += (size_t)256 * 256 * 9 / 2;
    float* wtdef1 = (float*)(ws + o); o += (size_t)256 * 256 * 9 / 2;
    float* wtdef2 = (float*)(ws + o); o += (size_t)256 * 256 * 9 / 2;
    float* wtpred = (float*)(ws + o); o += (size_t)128 * 128 * 9 / 2;
    if (ws_size < o * sizeof(double)) return;  // workspace too small

    auto cdiv = [](int a, int b) { return (a + b - 1) / b; };

    transpose_w_k<<<cdiv(256 * 256 * 9, 256), 256, 0, stream>>>(def_w[0], wtdef0, 256, 256);
    transpose_w_k<<<cdiv(256 * 256 * 9, 256), 256, 0, stream>>>(def_w[1], wtdef1, 256, 256);
    transpose_w_k<<<cdiv(256 * 256 * 9, 256), 256, 0, stream>>>(def_w[2], wtdef2, 256, 256);
    transpose_w_k<<<cdiv(128 * 128 * 9, 256), 256, 0, stream>>>(pred_w, wtpred, 128, 128);
    const float* wtdef[3] = {wtdef0, wtdef1, wtdef2};

    dim3 dgrid(WD / 16, HD, BATCH);

    for (int branch = 0; branch < 2; ++branch) {
        int a0 = (branch == 0) ? 0 : 1;
        double* offsetN  = (branch == 0) ? offset0 : offset1;
        double* deformN  = (branch == 0) ? deform0 : deform1;
        double* wbufN    = (branch == 0) ? w0buf : w1buf;
        const float* xy  = (branch == 0) ? inputs : inputs + 128 * HW;

        pack_feat_d<<<cdiv(BATCH * 256 * HW, 256), 256, 0, stream>>>(inputs, featA, a0);

        double* cur = featA;
        double* nxt = featB;
        for (int i = 0; i < 3; ++i) {
            conv3x3_direct_d<<<cdiv(BATCH * 18 * HW, 256), 256, 0, stream>>>(
                cur, 256 * HW, off_w[i], offb, 256, 18, 0);
            deform_gemm_d<256, 32, double><<<dgrid, 256, 0, stream>>>(
                cur, 256 * HW, offb, wtdef[i], nxt, 256);
            double* tmp = cur; cur = nxt; nxt = tmp;
        }
        conv3x3_direct_d<<<cdiv(BATCH * 18 * HW, 256), 256, 0, stream>>>(
            cur, 256 * HW, off_w[3], offsetN, 256, 18, 0);

        deform_gemm_d<128, 32, float><<<dgrid, 128, 0, stream>>>(
            xy, 2 * 128 * HW, offsetN, wtpred, deformN, 128);

        conv3x3_direct_d<<<cdiv(BATCH * 64 * HW, 256), 256, 0, stream>>>(
            deformN, 128 * HW, s_w[0], s1, 128, 64, 1);
        conv3x3_direct_d<<<cdiv(BATCH * 32 * HW, 256), 256, 0, stream>>>(
            s1, 64 * HW, s_w[1], s2, 64, 32, 1);
        conv3x3_direct_d<<<cdiv(BATCH * 1 * HW, 256), 256, 0, stream>>>(
            s2, 32 * HW, s_w[2], wbufN, 32, 1, 1);
    }

    fuse_d<<<cdiv(BATCH * 128 * HW, 256), 256, 0, stream>>>(
        deform0, deform1, w0buf, w1buf, out);
}